// Round 19
// baseline (246.527 us; speedup 1.0000x reference)
//
#include <hip/hip_runtime.h>
#include <math.h>

#define NNODES 50000
#define NEDGES 800000
#define INC    300
#define NGRAPH 256

typedef __attribute__((ext_vector_type(8))) short bf16x8;
typedef __attribute__((ext_vector_type(4))) short bf16x4;
typedef __attribute__((ext_vector_type(4))) float f32x4;

#define L2E8 0.180336880f   // 0.125 * log2(e)
#define SW(row, k) ((k) ^ (((row) & 7) << 3))
#define EB 3125             // edge blocks (800000/256)
#define FRONT_BLOCKS 782    // front blocks (50000/64)
#define FF_GRID (FRONT_BLOCKS + EB)

__device__ __forceinline__ unsigned short f2bf(float f) {
    unsigned u = __float_as_uint(f);
    u += 0x7fffu + ((u >> 16) & 1u);
    return (unsigned short)(u >> 16);
}
__device__ __forceinline__ float bf2f(unsigned short h) {
    return __uint_as_float(((unsigned)h) << 16);
}

// ---------------- k_setup: hist ∥ weight images + biases ----------------
struct WTArgs {
    const float* w[11];
    unsigned short* o[11];
    int K[11];
    int N[11];
    int mode[11];   // 0 plain [N][K]; 1 enc image; 2 128x128 image
    int roff[11];
    const float* syn_b; const float* ant_b;
    const float* c1q; const float* c1k; const float* c1v; const float* c1s;
    const float* c2q; const float* c2k; const float* c2v; const float* c2s;
    float* enc_b;   // [128]
    float* c1_b;    // [512]
    float* c2_b;    // [256]
};

__global__ void k_setup(WTArgs a, const int* __restrict__ dstv, int* __restrict__ deg) {
    int bx = blockIdx.x;
    if (bx < EB) {
        int e = bx * 256 + threadIdx.x;
        if (e < NEDGES) atomicAdd(&deg[dstv[e]], 1);
        return;
    }
    bx -= EB;
    int which = bx / 75;
    int sub = bx - which * 75;
    if (which == 11) {
        if (sub != 0) return;
        int t = threadIdx.x;
        for (int u = t; u < 896; u += 256) {
            if (u < 512) {
                int s = u >> 7, r = u & 127;
                const float* p = (s == 0) ? a.c1q : (s == 1) ? a.c1k : (s == 2) ? a.c1v : a.c1s;
                a.c1_b[u] = p[r];
            } else if (u < 768) {
                int v = u - 512;
                int s = v >> 6, r = v & 63;
                const float* p = (s == 0) ? a.c2q : (s == 1) ? a.c2k : (s == 2) ? a.c2v : a.c2s;
                a.c2_b[v] = p[r];
            } else {
                int v = u - 768;
                a.enc_b[v] = (v < 64) ? a.syn_b[v] : a.ant_b[v - 64];
            }
        }
        return;
    }
    int i = sub * 256 + threadIdx.x;
    int K = a.K[which], N = a.N[which];
    if (i >= K * N) return;
    int k = i / N, n = i - k * N;
    unsigned short v = f2bf(a.w[which][i]);
    size_t dst;
    int m = a.mode[which];
    if (m == 1) {
        int row = a.roff[which] + n;
        dst = (size_t)(k >> 6) * 8192 + row * 64 + SW(row, k & 63);
    } else if (m == 2) {
        dst = (size_t)n * 128 + SW(n, k);
    } else {
        dst = (size_t)n * K + k;
    }
    a.o[which][dst] = v;
}

// ---------------- scans (scan2 folded into scan3) ----------------
__global__ void k_scan1(const int* __restrict__ deg, int* __restrict__ ex,
                        int* __restrict__ bsum, int n) {
    __shared__ int tmp[256];
    int i = blockIdx.x * 256 + threadIdx.x;
    int v = (i < n) ? deg[i] : 0;
    tmp[threadIdx.x] = v;
    __syncthreads();
    for (int off = 1; off < 256; off <<= 1) {
        int t = (threadIdx.x >= off) ? tmp[threadIdx.x - off] : 0;
        __syncthreads();
        tmp[threadIdx.x] += t;
        __syncthreads();
    }
    if (i < n) ex[i] = tmp[threadIdx.x] - v;
    if (threadIdx.x == 255) bsum[blockIdx.x] = tmp[255];
}

__global__ void k_scan3(int* __restrict__ rp, const int* __restrict__ bsum,
                        int* __restrict__ cursor, int n, int E, int nb) {
    __shared__ int tmp[256];
    int t = threadIdx.x;
    int v = (t < nb && t < (int)blockIdx.x) ? bsum[t] : 0;
    tmp[t] = v;
    __syncthreads();
    for (int off = 128; off > 0; off >>= 1) {
        if (t < off) tmp[t] += tmp[t + off];
        __syncthreads();
    }
    int boff = tmp[0];
    int i = blockIdx.x * 256 + t;
    if (i < n) {
        int r = rp[i] + boff;
        rp[i] = r;
        cursor[i] = r;
    }
    if (i == 0) rp[n] = E;
}

// ---------------- k_front_fill: front (48 KB, full-tile GEMM2/3, GEMM1 B-dbuf, A direct) ∥ fill ----------------
__global__ __launch_bounds__(256) void k_front_fill(
    const float* __restrict__ x,
    const unsigned short* __restrict__ enc_img, const float* __restrict__ enc_b,
    const unsigned short* __restrict__ fus_img, const float* __restrict__ fus_b,
    const unsigned short* __restrict__ c1_img, const float* __restrict__ c1_b,
    unsigned short* __restrict__ qkvs1, int M,
    const int* __restrict__ src, const int* __restrict__ dstv,
    int* __restrict__ cursor, int* __restrict__ esrc)
{
    const int b = blockIdx.x;
    const int q = b / 5, r5 = b - q * 5;
    const int tid = threadIdx.x;
    if (!(r5 == 0 && q < FRONT_BLOCKS)) {   // ---- fill branch ----
        int nf = (b + 4) / 5;
        if (nf > FRONT_BLOCKS) nf = FRONT_BLOCKS;
        int e = (b - nf) * 256 + tid;
        if (e < NEDGES) {
            int d = dstv[e];
            int p = atomicAdd(&cursor[d], 1);
            esrc[p] = src[e];
        }
        return;
    }
    // ---- front branch: 48 KB LDS ----
    __shared__ __align__(16) short P[24576];   // 48 KB
    short* bufI = P;                // [64][128], 16 KB
    short* B0   = P + 8192;         // 16 KB
    short* B1   = P + 16384;        // 16 KB
    short* Bt   = P + 8192;         // 32 KB view (GEMM2/3)
    const int bm = q * 64;
    const int l  = tid & 63;
    const int wv = tid >> 6;
    const int fr = l & 15;
    const int fg = l >> 4;

    // A-panel: 10 fragments loaded directly from x at block start, cvt bf16 in regs
    bf16x8 aP[10];
    {
        int row = bm + wv * 16 + fr;
        if (row >= M) row = M - 1;       // clamp; epilogue guards stores
        const float* xr = x + (size_t)row * INC + fg * 8;
        #pragma unroll
        for (int t = 0; t < 9; ++t) {
            float4 u0 = *reinterpret_cast<const float4*>(xr + t * 32);
            float4 u1 = *reinterpret_cast<const float4*>(xr + t * 32 + 4);
            bf16x8 f;
            f[0] = (short)f2bf(u0.x); f[1] = (short)f2bf(u0.y);
            f[2] = (short)f2bf(u0.z); f[3] = (short)f2bf(u0.w);
            f[4] = (short)f2bf(u1.x); f[5] = (short)f2bf(u1.y);
            f[6] = (short)f2bf(u1.z); f[7] = (short)f2bf(u1.w);
            aP[t] = f;
        }
        bf16x8 f9 = (bf16x8){0, 0, 0, 0, 0, 0, 0, 0};
        int c0 = 288 + fg * 8;
        #pragma unroll
        for (int j = 0; j < 8; ++j) {
            int c = c0 + j;
            if (c < INC) f9[j] = (short)f2bf(x[(size_t)row * INC + c]);
        }
        aP[9] = f9;
    }

    // ---------- GEMM1: relu(x @ enc^T + enc_b), K=320 (padded), 5 dbuf phases ----------
    f32x4 acc1[8];
    #pragma unroll
    for (int j = 0; j < 8; ++j) acc1[j] = (f32x4){0.f, 0.f, 0.f, 0.f};

    // prologue: stage tile 0
    {
        bf16x8* d = (bf16x8*)B0;
        const bf16x8* s = (const bf16x8*)enc_img;
        #pragma unroll
        for (int i = 0; i < 4; ++i) d[tid + i * 256] = s[tid + i * 256];
    }
    __syncthreads();
    for (int ph = 0; ph < 5; ++ph) {
        short* cur = (ph & 1) ? B1 : B0;
        short* nxt = (ph & 1) ? B0 : B1;
        bf16x8 tmp[4];
        if (ph < 4) {   // T14: issue next tile's loads before compute
            const bf16x8* s = (const bf16x8*)(enc_img + (ph + 1) * 8192);
            #pragma unroll
            for (int i = 0; i < 4; ++i) tmp[i] = s[tid + i * 256];
        }
        #pragma unroll
        for (int ks = 0; ks < 2; ++ks) {
            int kk = ks * 32 + fg * 8;
            int t = ph * 2 + ks;
            #pragma unroll
            for (int nj = 0; nj < 8; ++nj) {
                int br = nj * 16 + fr;
                bf16x8 bfr = *reinterpret_cast<const bf16x8*>(cur + br * 64 + SW(br, kk));
                acc1[nj] = __builtin_amdgcn_mfma_f32_16x16x32_bf16(aP[t], bfr, acc1[nj], 0, 0, 0);
            }
        }
        if (ph < 4) {
            bf16x8* d = (bf16x8*)nxt;
            #pragma unroll
            for (int i = 0; i < 4; ++i) d[tid + i * 256] = tmp[i];
        }
        __syncthreads();
    }
    // relu + cast -> bufI (swizzled [64][128])
    #pragma unroll
    for (int nj = 0; nj < 8; ++nj) {
        int col = nj * 16 + fr;
        float bv = enc_b[col];
        #pragma unroll
        for (int r = 0; r < 4; ++r) {
            int row = wv * 16 + fg * 4 + r;
            float val = fmaxf(acc1[nj][r] + bv, 0.f);
            bufI[row * 128 + SW(row, col)] = (short)f2bf(val);
        }
    }
    __syncthreads();

    // ---------- GEMM2: xfus = bufI @ fus^T + fus_b, K=128, one full-tile phase ----------
    bf16x8 af[4];
    {
        int ar = wv * 16 + fr;
        #pragma unroll
        for (int t = 0; t < 4; ++t)
            af[t] = *reinterpret_cast<const bf16x8*>(bufI + ar * 128 + SW(ar, fg * 8 + t * 32));
    }
    __syncthreads();   // af loads done before Bt (aliases B0/B1) is overwritten
    {
        bf16x8* d = (bf16x8*)Bt;
        const bf16x8* s = (const bf16x8*)fus_img;
        #pragma unroll
        for (int i = 0; i < 8; ++i) d[tid + i * 256] = s[tid + i * 256];
    }
    __syncthreads();

    f32x4 acc2[8];
    #pragma unroll
    for (int j = 0; j < 8; ++j) acc2[j] = (f32x4){0.f, 0.f, 0.f, 0.f};
    #pragma unroll
    for (int t = 0; t < 4; ++t) {
        int k = t * 32 + fg * 8;
        #pragma unroll
        for (int nj = 0; nj < 8; ++nj) {
            int br = nj * 16 + fr;
            bf16x8 bfr = *reinterpret_cast<const bf16x8*>(Bt + br * 128 + SW(br, k));
            acc2[nj] = __builtin_amdgcn_mfma_f32_16x16x32_bf16(af[t], bfr, acc2[nj], 0, 0, 0);
        }
    }
    __syncthreads();
    // xfus -> bufI (overwrite; af in regs)
    #pragma unroll
    for (int nj = 0; nj < 8; ++nj) {
        int col = nj * 16 + fr;
        float bv = fus_b[col];
        #pragma unroll
        for (int r = 0; r < 4; ++r) {
            int row = wv * 16 + fg * 4 + r;
            bufI[row * 128 + SW(row, col)] = (short)f2bf(acc2[nj][r] + bv);
        }
    }
    __syncthreads();

    // ---------- GEMM3: qkvs = bufI @ c1^T + c1_b, 4 full-tile phases, bounce-store ----------
    bf16x8 af2[4];
    {
        int ar = wv * 16 + fr;
        #pragma unroll
        for (int t = 0; t < 4; ++t)
            af2[t] = *reinterpret_cast<const bf16x8*>(bufI + ar * 128 + SW(ar, fg * 8 + t * 32));
    }

    #pragma unroll
    for (int cc = 0; cc < 4; ++cc) {
        __syncthreads();   // af2 loads done (cc=0) / prior bounce+store reads done
        {
            bf16x8* d = (bf16x8*)Bt;
            const bf16x8* s = (const bf16x8*)(c1_img + cc * 16384);
            #pragma unroll
            for (int i = 0; i < 8; ++i) d[tid + i * 256] = s[tid + i * 256];
        }
        __syncthreads();
        f32x4 acc3[8];
        #pragma unroll
        for (int j = 0; j < 8; ++j) acc3[j] = (f32x4){0.f, 0.f, 0.f, 0.f};
        #pragma unroll
        for (int t = 0; t < 4; ++t) {
            int k = t * 32 + fg * 8;
            #pragma unroll
            for (int nj = 0; nj < 8; ++nj) {
                int br = nj * 16 + fr;
                bf16x8 bfr = *reinterpret_cast<const bf16x8*>(Bt + br * 128 + SW(br, k));
                acc3[nj] = __builtin_amdgcn_mfma_f32_16x16x32_bf16(af2[t], bfr, acc3[nj], 0, 0, 0);
            }
        }
        // bounce: acc -> bufI linear [64][128] (af2 in regs, bufI reads done)
        #pragma unroll
        for (int nj = 0; nj < 8; ++nj) {
            int col = nj * 16 + fr;
            float bv = c1_b[cc * 128 + col];
            #pragma unroll
            for (int r = 0; r < 4; ++r) {
                int row = wv * 16 + fg * 4 + r;
                bufI[row * 128 + col] = (short)f2bf(acc3[nj][r] + bv);
            }
        }
        __syncthreads();
        // coalesced 16B/lane store
        #pragma unroll
        for (int i = 0; i < 4; ++i) {
            int p = tid + i * 256;
            int row = p >> 4;
            int c8 = (p & 15) * 8;
            int gr = bm + row;
            if (gr < M)
                *reinterpret_cast<bf16x8*>(qkvs1 + (size_t)gr * 512 + cc * 128 + c8) =
                    *reinterpret_cast<const bf16x8*>(bufI + row * 128 + c8);
        }
    }
}

// ---------------- LDS MFMA GEMM (conv2), swizzled, bounce-store epilogue ----------------
#define BM 128

template<int BNT>
__global__ __launch_bounds__(256) void gemm_mfma(
    const unsigned short* __restrict__ A, int lda, int M, int K,
    const unsigned short* __restrict__ Wt,
    const float* __restrict__ bias,
    unsigned short* __restrict__ C, int ldc)
{
    __shared__ __align__(16) short As[BM * 64];
    __shared__ __align__(16) short Bs[BNT * 64];
    const int tid = threadIdx.x;
    const int bm = blockIdx.x * BM;
    const int bn = blockIdx.y * BNT;
    const int tr = tid >> 4;
    const int tc = (tid & 15) * 4;
    const int l  = tid & 63;
    const int wv = tid >> 6;
    const int fr = l & 15;
    const int fg = l >> 4;

    f32x4 acc[2][BNT / 16];
    #pragma unroll
    for (int i = 0; i < 2; ++i)
        #pragma unroll
        for (int j = 0; j < BNT / 16; ++j) acc[i][j] = (f32x4){0.f, 0.f, 0.f, 0.f};

    for (int k0 = 0; k0 < K; k0 += 64) {
        #pragma unroll
        for (int p = 0; p < 8; ++p) {
            int row = p * 16 + tr;
            int grow = bm + row;
            int k = k0 + tc;
            bf16x4 s4 = (bf16x4){0, 0, 0, 0};
            if (grow < M) s4 = *reinterpret_cast<const bf16x4*>(A + (size_t)grow * lda + k);
            *reinterpret_cast<bf16x4*>(As + row * 64 + SW(row, tc)) = s4;
        }
        #pragma unroll
        for (int p = 0; p < BNT / 16; ++p) {
            int n = p * 16 + tr;
            *reinterpret_cast<bf16x4*>(Bs + n * 64 + SW(n, tc)) =
                *reinterpret_cast<const bf16x4*>(Wt + (size_t)(bn + n) * K + k0 + tc);
        }
        __syncthreads();
        #pragma unroll
        for (int ks = 0; ks < 2; ++ks) {
            int kk = ks * 32 + fg * 8;
            int ar0 = wv * 32 + fr, ar1 = wv * 32 + 16 + fr;
            bf16x8 a0 = *reinterpret_cast<const bf16x8*>(As + ar0 * 64 + SW(ar0, kk));
            bf16x8 a1 = *reinterpret_cast<const bf16x8*>(As + ar1 * 64 + SW(ar1, kk));
            #pragma unroll
            for (int nj = 0; nj < BNT / 16; ++nj) {
                int br = nj * 16 + fr;
                bf16x8 b = *reinterpret_cast<const bf16x8*>(Bs + br * 64 + SW(br, kk));
                acc[0][nj] = __builtin_amdgcn_mfma_f32_16x16x32_bf16(a0, b, acc[0][nj], 0, 0, 0);
                acc[1][nj] = __builtin_amdgcn_mfma_f32_16x16x32_bf16(a1, b, acc[1][nj], 0, 0, 0);
            }
        }
        __syncthreads();
    }
    #pragma unroll
    for (int mi = 0; mi < 2; ++mi) {
        #pragma unroll
        for (int nj = 0; nj < BNT / 16; ++nj) {
            int col = nj * 16 + fr;
            float bv = bias[bn + col];
            #pragma unroll
            for (int r = 0; r < 4; ++r) {
                int lr = wv * 16 + fg * 4 + r;
                As[lr * BNT + col] = (short)f2bf(acc[mi][nj][r] + bv);
            }
        }
        __syncthreads();
        #pragma unroll
        for (int i = 0; i < 4; ++i) {
            int p = tid + i * 256;
            int lr = p >> 4;
            int c8 = (p & 15) * 8;
            int grow = bm + (lr >> 4) * 32 + mi * 16 + (lr & 15);
            if (grow < M)
                *reinterpret_cast<bf16x8*>(C + (size_t)grow * ldc + bn + c8) =
                    *reinterpret_cast<const bf16x8*>(As + lr * BNT + c8);
        }
        __syncthreads();
    }
}

// ---------------- attention, heads=2; prefetch depth 2 ----------------
__global__ __launch_bounds__(256) void attn_h2(
    const unsigned short* __restrict__ qkvs,
    const int* __restrict__ rowptr, const int* __restrict__ esrc,
    unsigned short* __restrict__ outp, int N)
{
    int wid = (blockIdx.x * blockDim.x + threadIdx.x) >> 6;
    int l = threadIdx.x & 63;
    if (wid >= N) return;
    const int sl = l & 15;
    const int g  = l >> 4;
    const unsigned short* bi = qkvs + (size_t)wid * 512;
    float q[8];
    {
        bf16x8 qv = *reinterpret_cast<const bf16x8*>(bi + 8 * sl);
        #pragma unroll
        for (int i = 0; i < 8; ++i) q[i] = bf2f((unsigned short)qv[i]) * L2E8;
    }
    float s = 0.f;
    float acc[8] = {0.f, 0.f, 0.f, 0.f, 0.f, 0.f, 0.f, 0.f};
    const int beg = rowptr[wid], end = rowptr[wid + 1];
    const int iters = (end - beg + 3) >> 2;
    int e = beg + g;
    bool va0 = e < end;
    int j0 = va0 ? esrc[e] : wid;
    const unsigned short* pp0 = qkvs + (size_t)j0 * 512 + 8 * sl;
    bf16x8 ka = *reinterpret_cast<const bf16x8*>(pp0 + 128);
    bf16x8 vva = *reinterpret_cast<const bf16x8*>(pp0 + 256);
    bool va1 = (e + 4) < end;
    int j1 = va1 ? esrc[e + 4] : wid;
    const unsigned short* pp1 = qkvs + (size_t)j1 * 512 + 8 * sl;
    bf16x8 kb = *reinterpret_cast<const bf16x8*>(pp1 + 128);
    bf16x8 vvb = *reinterpret_cast<const bf16x8*>(pp1 + 256);
    for (int it = 0; it < iters; ++it) {
        bf16x8 kc = ka, vc = vva;
        bool vd = va0;
        ka = kb; vva = vvb; va0 = va1;
        va1 = (e + 8) < end;
        int j2 = va1 ? esrc[e + 8] : wid;
        const unsigned short* p2 = qkvs + (size_t)j2 * 512 + 8 * sl;
        kb = *reinterpret_cast<const bf16x8*>(p2 + 128);
        vvb = *reinterpret_cast<const bf16x8*>(p2 + 256);
        e += 4;
        float p = 0.f;
        #pragma unroll
        for (int i = 0; i < 8; ++i) p += q[i] * bf2f((unsigned short)kc[i]);
        p += __shfl_xor(p, 1, 64);
        p += __shfl_xor(p, 2, 64);
        p += __shfl_xor(p, 4, 64);
        float w = vd ? __builtin_amdgcn_exp2f(p) : 0.f;
        s += w;
        #pragma unroll
        for (int i = 0; i < 8; ++i) acc[i] += w * bf2f((unsigned short)vc[i]);
    }
    #pragma unroll
    for (int mask = 16; mask <= 32; mask <<= 1) {
        s += __shfl_xor(s, mask, 64);
        #pragma unroll
        for (int i = 0; i < 8; ++i) acc[i] += __shfl_xor(acc[i], mask, 64);
    }
    if (g == 0) {
        float inv = 1.f / (s + 1e-16f);
        bf16x8 sv = *reinterpret_cast<const bf16x8*>(bi + 384 + 8 * sl);
        bf16x8 o;
        #pragma unroll
        for (int i = 0; i < 8; ++i) {
            float r = fmaxf(acc[i] * inv + bf2f((unsigned short)sv[i]), 0.f);
            o[i] = (short)f2bf(r);
        }
        *reinterpret_cast<bf16x8*>(outp + (size_t)wid * 128 + 8 * sl) = o;
    }
}

// ---------------- attention, heads=1; prefetch depth 2 ----------------
__global__ __launch_bounds__(256) void attn_h1(
    const unsigned short* __restrict__ qkvs,
    const int* __restrict__ rowptr, const int* __restrict__ esrc,
    float* __restrict__ outp, int N)
{
    int wid = (blockIdx.x * blockDim.x + threadIdx.x) >> 6;
    int l = threadIdx.x & 63;
    if (wid >= N) return;
    const int sl = l & 7;
    const int g  = l >> 3;
    const unsigned short* bi = qkvs + (size_t)wid * 256;
    float q[8];
    {
        bf16x8 qv = *reinterpret_cast<const bf16x8*>(bi + 8 * sl);
        #pragma unroll
        for (int i = 0; i < 8; ++i) q[i] = bf2f((unsigned short)qv[i]) * L2E8;
    }
    float s = 0.f;
    float acc[8] = {0.f, 0.f, 0.f, 0.f, 0.f, 0.f, 0.f, 0.f};
    const int beg = rowptr[wid], end = rowptr[wid + 1];
    const int iters = (end - beg + 7) >> 3;
    int e = beg + g;
    bool va0 = e < end;
    int j0 = va0 ? esrc[e] : wid;
    const unsigned short* pp0 = qkvs + (size_t)j0 * 256 + 8 * sl;
    bf16x8 ka = *reinterpret_cast<const bf16x8*>(pp0 + 64);
    bf16x8 vva = *reinterpret_cast<const bf16x8*>(pp0 + 128);
    bool va1 = (e + 8) < end;
    int j1 = va1 ? esrc[e + 8] : wid;
    const unsigned short* pp1 = qkvs + (size_t)j1 * 256 + 8 * sl;
    bf16x8 kb = *reinterpret_cast<const bf16x8*>(pp1 + 64);
    bf16x8 vvb = *reinterpret_cast<const bf16x8*>(pp1 + 128);
    for (int it = 0; it < iters; ++it) {
        bf16x8 kc = ka, vc = vva;
        bool vd = va0;
        ka = kb; vva = vvb; va0 = va1;
        va1 = (e + 16) < end;
        int j2 = va1 ? esrc[e + 16] : wid;
        const unsigned short* p2 = qkvs + (size_t)j2 * 256 + 8 * sl;
        kb = *reinterpret_cast<const bf16x8*>(p2 + 64);
        vvb = *reinterpret_cast<const bf16x8*>(p2 + 128);
        e += 8;
        float p = 0.f;
        #pragma unroll
        for (int i = 0; i < 8; ++i) p += q[i] * bf2f((unsigned short)kc[i]);
        p += __shfl_xor(p, 1, 64);
        p += __shfl_xor(p, 2, 64);
        p += __shfl_xor(p, 4, 64);
        float w = vd ? __builtin_amdgcn_exp2f(p) : 0.f;
        s += w;
        #pragma unroll
        for (int i = 0; i < 8; ++i) acc[i] += w * bf2f((unsigned short)vc[i]);
    }
    #pragma unroll
    for (int mask = 8; mask <= 32; mask <<= 1) {
        s += __shfl_xor(s, mask, 64);
        #pragma unroll
        for (int i = 0; i < 8; ++i) acc[i] += __shfl_xor(acc[i], mask, 64);
    }
    if (g == 0) {
        float inv = 1.f / (s + 1e-16f);
        float r[8];
        #pragma unroll
        for (int i = 0; i < 8; ++i)
            r[i] = acc[i] * inv + bf2f(bi[192 + 8 * sl + i]);
        float* op = outp + (size_t)wid * 64 + 8 * sl;
        *reinterpret_cast<float4*>(op)     = make_float4(r[0], r[1], r[2], r[3]);
        *reinterpret_cast<float4*>(op + 4) = make_float4(r[4], r[5], r[6], r[7]);
    }
}

// ---------------- fused global mean pool + head MLP ----------------
__device__ __forceinline__ int lbound(const int* __restrict__ a, int n, int key) {
    int lo = 0, hi = n;
    while (lo < hi) {
        int mid = (lo + hi) >> 1;
        if (a[mid] < key) lo = mid + 1; else hi = mid;
    }
    return lo;
}

__global__ void pool_head(const float* __restrict__ h, const int* __restrict__ batch,
                          const float* __restrict__ l1W, const float* __restrict__ l1b,
                          const float* __restrict__ l2W, const float* __restrict__ l2b,
                          float* __restrict__ out) {
    __shared__ float red[4][64];
    int g = blockIdx.x;
    int l = threadIdx.x & 63;
    int w = threadIdx.x >> 6;
    int lo = lbound(batch, NNODES, g);
    int hi = lbound(batch, NNODES, g + 1);
    float s = 0.f;
    for (int i = lo + w; i < hi; i += 4) s += h[(size_t)i * 64 + l];
    red[w][l] = s;
    __syncthreads();
    if (w == 0) {
        float t = red[0][l] + red[1][l] + red[2][l] + red[3][l];
        float cnt = (float)((hi - lo) > 1 ? (hi - lo) : 1);
        float p = t / cnt;
        float hsum = l1b[l];
        #pragma unroll
        for (int kk = 0; kk < 64; ++kk) {
            float pk = __shfl(p, kk, 64);
            hsum += pk * l1W[kk * 64 + l];
        }
        float hr = fmaxf(hsum, 0.f);
        float o0 = hr * l2W[l * 2 + 0];
        float o1 = hr * l2W[l * 2 + 1];
        #pragma unroll
        for (int off = 32; off > 0; off >>= 1) {
            o0 += __shfl_xor(o0, off, 64);
            o1 += __shfl_xor(o1, off, 64);
        }
        if (l == 0) {
            out[g * 2 + 0] = o0 + l2b[0];
            out[g * 2 + 1] = o1 + l2b[1];
        }
    }
}

// ---------------- host launch ----------------
extern "C" void kernel_launch(void* const* d_in, const int* in_sizes, int n_in,
                              void* d_out, int out_size, void* d_ws, size_t ws_size,
                              hipStream_t stream) {
    const float* x      = (const float*)d_in[0];
    const int*   ei     = (const int*)d_in[1];
    const int*   batch  = (const int*)d_in[2];
    const float* syn_W  = (const float*)d_in[3];  const float* syn_b = (const float*)d_in[4];
    const float* ant_W  = (const float*)d_in[5];  const float* ant_b = (const float*)d_in[6];
    const float* fus_W  = (const float*)d_in[7];  const float* fus_b = (const float*)d_in[8];
    const float* c1_Wq  = (const float*)d_in[9];  const float* c1_bq = (const float*)d_in[10];
    const float* c1_Wk  = (const float*)d_in[11]; const float* c1_bk = (const float*)d_in[12];
    const float* c1_Wv  = (const float*)d_in[13]; const float* c1_bv = (const float*)d_in[14];
    const float* c1_Ws  = (const float*)d_in[15]; const float* c1_bs = (const float*)d_in[16];
    const float* c2_Wq  = (const float*)d_in[17]; const float* c2_bq = (const float*)d_in[18];
    const float* c2_Wk  = (const float*)d_in[19]; const float* c2_bk = (const float*)d_in[20];
    const float* c2_Wv  = (const float*)d_in[21]; const float* c2_bv = (const float*)d_in[22];
    const float* c2_Ws  = (const float*)d_in[23]; const float* c2_bs = (const float*)d_in[24];
    const float* l1_W   = (const float*)d_in[25]; const float* l1_b  = (const float*)d_in[26];
    const float* l2_W   = (const float*)d_in[27]; const float* l2_b  = (const float*)d_in[28];
    const int* src = ei;
    const int* dst = ei + NEDGES;
    float* out = (float*)d_out;

    char* ws = (char*)d_ws;
    size_t off = 0;
    auto alloc = [&](size_t bytes) -> char* {
        char* p = ws + off;
        off += (bytes + 255) & ~((size_t)255);
        return p;
    };

    unsigned short* H     = (unsigned short*)alloc((size_t)NNODES * 128 * 2);
    unsigned short* H2b   = (unsigned short*)alloc((size_t)NNODES * 128 * 2);
    unsigned short* qkvs1 = (unsigned short*)alloc((size_t)NNODES * 512 * 2);
    unsigned short* qkvs2 = (unsigned short*)alloc((size_t)NNODES * 256 * 2);
    unsigned short* fus_img = (unsigned short*)alloc((size_t)16384 * 2);
    unsigned short* c1_img  = (unsigned short*)alloc((size_t)4 * 16384 * 2);
    unsigned short* c2w_t   = (unsigned short*)alloc((size_t)256 * 128 * 2);
    float* enc_b = (float*)alloc(128 * 4);
    float* c1_b  = (float*)alloc(512 * 4);
    float* c2_b  = (float*)alloc(256 * 4);
    int*   cursor = (int*)alloc((NNODES + 1) * 4);
    int*   rowptr = (int*)alloc((NNODES + 1) * 4);
    int*   bsum   = (int*)alloc(256 * 4);
    int*   esrc   = (int*)alloc((size_t)NEDGES * 4);
    // ---- contiguous zero region: deg | enc_img ----
    char* zbase = ws + off;
    int*   deg     = (int*)alloc((NNODES + 1) * 4);
    unsigned short* enc_img = (unsigned short*)alloc((size_t)5 * 8192 * 2);
    size_t zspan = (size_t)((ws + off) - zbase);

    const int NB = (NNODES + 255) / 256;
    dim3 t256(256);

    WTArgs wa;
    wa.w[0] = syn_W;  wa.o[0] = enc_img;  wa.K[0] = 300; wa.N[0] = 64;  wa.mode[0] = 1; wa.roff[0] = 0;
    wa.w[1] = ant_W;  wa.o[1] = enc_img;  wa.K[1] = 300; wa.N[1] = 64;  wa.mode[1] = 1; wa.roff[1] = 64;
    wa.w[2] = fus_W;  wa.o[2] = fus_img;  wa.K[2] = 128; wa.N[2] = 128; wa.mode[2] = 2; wa.roff[2] = 0;
    wa.w[3] = c1_Wq;  wa.o[3] = c1_img + 0 * 16384; wa.K[3] = 128; wa.N[3] = 128; wa.mode[3] = 2; wa.roff[3] = 0;
    wa.w[4] = c1_Wk;  wa.o[4] = c1_img + 1 * 16384; wa.K[4] = 128; wa.N[4] = 128; wa.mode[4] = 2; wa.roff[4] = 0;
    wa.w[5] = c1_Wv;  wa.o[5] = c1_img + 2 * 16384; wa.K[5] = 128; wa.N[5] = 128; wa.mode[5] = 2; wa.roff[5] = 0;
    wa.w[6] = c1_Ws;  wa.o[6] = c1_img + 3 * 16384; wa.K[6] = 128; wa.N[6] = 128; wa.mode[6] = 2; wa.roff[6] = 0;
    wa.w[7] = c2_Wq;  wa.o[7] = c2w_t + 0 * 64 * 128;  wa.K[7] = 128; wa.N[7] = 64; wa.mode[7] = 0; wa.roff[7] = 0;
    wa.w[8] = c2_Wk;  wa.o[8] = c2w_t + 1 * 64 * 128;  wa.K[8] = 128; wa.N[8] = 64; wa.mode[8] = 0; wa.roff[8] = 0;
    wa.w[9] = c2_Wv;  wa.o[9] = c2w_t + 2 * 64 * 128;  wa.K[9] = 128; wa.N[9] = 64; wa.mode[9] = 0; wa.roff[9] = 0;
    wa.w[10] = c2_Ws; wa.o[10] = c2w_t + 3 * 64 * 128; wa.K[10] = 128; wa.N[10] = 64; wa.mode[10] = 0; wa.roff[10] = 0;
    wa.syn_b = syn_b; wa.ant_b = ant_b;
    wa.c1q = c1_bq; wa.c1k = c1_bk; wa.c1v = c1_bv; wa.c1s = c1_bs;
    wa.c2q = c2_bq; wa.c2k = c2_bk; wa.c2v = c2_bv; wa.c2s = c2_bs;
    wa.enc_b = enc_b; wa.c1_b = c1_b; wa.c2_b = c2_b;

    // --- single memset for deg + enc_img(K-pad) ---
    hipMemsetAsync(zbase, 0, zspan, stream);
    // --- setup: hist ∥ weight images (independent) ---
    k_setup<<<EB + 900, t256, 0, stream>>>(wa, dst, deg);

    // --- scans (scan2 folded into scan3) ---
    k_scan1<<<NB, t256, 0, stream>>>(deg, rowptr, bsum, NNODES);
    k_scan3<<<NB, t256, 0, stream>>>(rowptr, bsum, cursor, NNODES, NEDGES, NB);

    // --- front (enc->fus->conv1) interleaved with fill ---
    k_front_fill<<<FF_GRID, t256, 0, stream>>>(
        x, enc_img, enc_b, fus_img, fus_b, c1_img, c1_b, qkvs1, NNODES,
        src, dst, cursor, esrc);

    // --- conv1 attention + relu -> H ---
    attn_h2<<<(NNODES * 64 + 255) / 256, t256, 0, stream>>>(qkvs1, rowptr, esrc, H, NNODES);

    // --- conv2 q|k|v|s, N=256 (BN=128, y=2) ---
    gemm_mfma<128><<<dim3((NNODES + BM - 1) / BM, 2), t256, 0, stream>>>(
        H, 128, NNODES, 128, c2w_t, c2_b, qkvs2, 256);

    // --- conv2 attention -> H2 (f32) ---
    float* H2 = (float*)H2b;
    attn_h1<<<(NNODES * 64 + 255) / 256, t256, 0, stream>>>(qkvs2, rowptr, esrc, H2, NNODES);

    // --- pool + head ---
    pool_head<<<NGRAPH, t256, 0, stream>>>(H2, batch, l1_W, l1_b, l2_W, l2_b, out);
}

// Round 20
// 240.521 us; speedup vs baseline: 1.0250x; 1.0250x over previous
//
#include <hip/hip_runtime.h>
#include <math.h>

#define NNODES 50000
#define NEDGES 800000
#define INC    300
#define NGRAPH 256

typedef __attribute__((ext_vector_type(8))) short bf16x8;
typedef __attribute__((ext_vector_type(4))) short bf16x4;
typedef __attribute__((ext_vector_type(4))) float f32x4;

#define L2E8 0.180336880f   // 0.125 * log2(e)
#define SW(row, k) ((k) ^ (((row) & 7) << 3))
#define EB 3125             // edge blocks (800000/256)
#define FRONT_BLOCKS 782    // front blocks (50000/64)
#define FF_GRID (FRONT_BLOCKS + EB)

__device__ __forceinline__ unsigned short f2bf(float f) {
    unsigned u = __float_as_uint(f);
    u += 0x7fffu + ((u >> 16) & 1u);
    return (unsigned short)(u >> 16);
}
__device__ __forceinline__ float bf2f(unsigned short h) {
    return __uint_as_float(((unsigned)h) << 16);
}

// ---------------- k_setup: hist ∥ weight images + biases ----------------
struct WTArgs {
    const float* w[11];
    unsigned short* o[11];
    int K[11];
    int N[11];
    int mode[11];   // 0 plain [N][K]; 1 enc image; 2 128x128 image
    int roff[11];
    const float* syn_b; const float* ant_b;
    const float* c1q; const float* c1k; const float* c1v; const float* c1s;
    const float* c2q; const float* c2k; const float* c2v; const float* c2s;
    float* enc_b;   // [128]
    float* c1_b;    // [512]
    float* c2_b;    // [256]
};

__global__ void k_setup(WTArgs a, const int* __restrict__ dstv, int* __restrict__ deg) {
    int bx = blockIdx.x;
    if (bx < EB) {
        int e = bx * 256 + threadIdx.x;
        if (e < NEDGES) atomicAdd(&deg[dstv[e]], 1);
        return;
    }
    bx -= EB;
    int which = bx / 75;
    int sub = bx - which * 75;
    if (which == 11) {
        if (sub != 0) return;
        int t = threadIdx.x;
        for (int u = t; u < 896; u += 256) {
            if (u < 512) {
                int s = u >> 7, r = u & 127;
                const float* p = (s == 0) ? a.c1q : (s == 1) ? a.c1k : (s == 2) ? a.c1v : a.c1s;
                a.c1_b[u] = p[r];
            } else if (u < 768) {
                int v = u - 512;
                int s = v >> 6, r = v & 63;
                const float* p = (s == 0) ? a.c2q : (s == 1) ? a.c2k : (s == 2) ? a.c2v : a.c2s;
                a.c2_b[v] = p[r];
            } else {
                int v = u - 768;
                a.enc_b[v] = (v < 64) ? a.syn_b[v] : a.ant_b[v - 64];
            }
        }
        return;
    }
    int i = sub * 256 + threadIdx.x;
    int K = a.K[which], N = a.N[which];
    if (i >= K * N) return;
    int k = i / N, n = i - k * N;
    unsigned short v = f2bf(a.w[which][i]);
    size_t dst;
    int m = a.mode[which];
    if (m == 1) {
        int row = a.roff[which] + n;
        dst = (size_t)(k >> 6) * 8192 + row * 64 + SW(row, k & 63);
    } else if (m == 2) {
        dst = (size_t)n * 128 + SW(n, k);
    } else {
        dst = (size_t)n * K + k;
    }
    a.o[which][dst] = v;
}

// ---------------- scans (scan2 folded into scan3) ----------------
__global__ void k_scan1(const int* __restrict__ deg, int* __restrict__ ex,
                        int* __restrict__ bsum, int n) {
    __shared__ int tmp[256];
    int i = blockIdx.x * 256 + threadIdx.x;
    int v = (i < n) ? deg[i] : 0;
    tmp[threadIdx.x] = v;
    __syncthreads();
    for (int off = 1; off < 256; off <<= 1) {
        int t = (threadIdx.x >= off) ? tmp[threadIdx.x - off] : 0;
        __syncthreads();
        tmp[threadIdx.x] += t;
        __syncthreads();
    }
    if (i < n) ex[i] = tmp[threadIdx.x] - v;
    if (threadIdx.x == 255) bsum[blockIdx.x] = tmp[255];
}

__global__ void k_scan3(int* __restrict__ rp, const int* __restrict__ bsum,
                        int* __restrict__ cursor, int n, int E, int nb) {
    __shared__ int tmp[256];
    int t = threadIdx.x;
    int v = (t < nb && t < (int)blockIdx.x) ? bsum[t] : 0;
    tmp[t] = v;
    __syncthreads();
    for (int off = 128; off > 0; off >>= 1) {
        if (t < off) tmp[t] += tmp[t + off];
        __syncthreads();
    }
    int boff = tmp[0];
    int i = blockIdx.x * 256 + t;
    if (i < n) {
        int r = rp[i] + boff;
        rp[i] = r;
        cursor[i] = r;
    }
    if (i == 0) rp[n] = E;
}

// ---------------- k_front_fill: front (32 KB LDS, T14 async-stage all 15 phases) ∥ fill ----------------
__global__ __launch_bounds__(256) void k_front_fill(
    const float* __restrict__ x,
    const unsigned short* __restrict__ enc_img, const float* __restrict__ enc_b,
    const unsigned short* __restrict__ fus_img, const float* __restrict__ fus_b,
    const unsigned short* __restrict__ c1_img, const float* __restrict__ c1_b,
    unsigned short* __restrict__ qkvs1, int M,
    const int* __restrict__ src, const int* __restrict__ dstv,
    int* __restrict__ cursor, int* __restrict__ esrc)
{
    const int b = blockIdx.x;
    const int q = b / 5, r5 = b - q * 5;
    const int tid = threadIdx.x;
    if (!(r5 == 0 && q < FRONT_BLOCKS)) {   // ---- fill branch ----
        int nf = (b + 4) / 5;
        if (nf > FRONT_BLOCKS) nf = FRONT_BLOCKS;
        int e = (b - nf) * 256 + tid;
        if (e < NEDGES) {
            int d = dstv[e];
            int p = atomicAdd(&cursor[d], 1);
            esrc[p] = src[e];
        }
        return;
    }
    // ---- front branch: 32 KB LDS ----
    __shared__ __align__(16) short P[16384];   // 32 KB
    short* bufI = P;            // [64][128], 16 KB
    short* Bh   = P + 8192;     // 16 KB staging buffer (all GEMMs)
    const int bm = q * 64;
    const int l  = tid & 63;
    const int wv = tid >> 6;
    const int fr = l & 15;
    const int fg = l >> 4;

    // A-panel: 10 fragments loaded directly from x at block start, cvt bf16 in regs
    bf16x8 aP[10];
    {
        int row = bm + wv * 16 + fr;
        if (row >= M) row = M - 1;
        const float* xr = x + (size_t)row * INC + fg * 8;
        #pragma unroll
        for (int t = 0; t < 9; ++t) {
            float4 u0 = *reinterpret_cast<const float4*>(xr + t * 32);
            float4 u1 = *reinterpret_cast<const float4*>(xr + t * 32 + 4);
            bf16x8 f;
            f[0] = (short)f2bf(u0.x); f[1] = (short)f2bf(u0.y);
            f[2] = (short)f2bf(u0.z); f[3] = (short)f2bf(u0.w);
            f[4] = (short)f2bf(u1.x); f[5] = (short)f2bf(u1.y);
            f[6] = (short)f2bf(u1.z); f[7] = (short)f2bf(u1.w);
            aP[t] = f;
        }
        bf16x8 f9 = (bf16x8){0, 0, 0, 0, 0, 0, 0, 0};
        int c0 = 288 + fg * 8;
        #pragma unroll
        for (int j = 0; j < 8; ++j) {
            int c = c0 + j;
            if (c < INC) f9[j] = (short)f2bf(x[(size_t)row * INC + c]);
        }
        aP[9] = f9;
    }

    // T14 staging regs: 4x16B per thread = one 16 KB tile per block
    bf16x8 tmp0, tmp1, tmp2, tmp3;
    #define LDT(srcp) { const bf16x8* s_ = (const bf16x8*)(srcp); \
        tmp0 = s_[tid]; tmp1 = s_[tid + 256]; tmp2 = s_[tid + 512]; tmp3 = s_[tid + 768]; }
    #define WRT() { bf16x8* d_ = (bf16x8*)Bh; \
        d_[tid] = tmp0; d_[tid + 256] = tmp1; d_[tid + 512] = tmp2; d_[tid + 768] = tmp3; }

    // prologue: stage enc tile 0
    LDT(enc_img);
    WRT();
    __syncthreads();

    // ---------- GEMM1: relu(x @ enc^T + enc_b), K=320 (padded), 5 phases ----------
    f32x4 acc1[8];
    #pragma unroll
    for (int j = 0; j < 8; ++j) acc1[j] = (f32x4){0.f, 0.f, 0.f, 0.f};

    for (int ph = 0; ph < 5; ++ph) {
        // issue NEXT stage's loads (enc ph+1, or fus half 0 after last enc phase)
        LDT(ph < 4 ? enc_img + (ph + 1) * 8192 : fus_img);
        #pragma unroll
        for (int ks = 0; ks < 2; ++ks) {
            int kk = ks * 32 + fg * 8;
            int t = ph * 2 + ks;
            #pragma unroll
            for (int nj = 0; nj < 8; ++nj) {
                int br = nj * 16 + fr;
                bf16x8 bfr = *reinterpret_cast<const bf16x8*>(Bh + br * 64 + SW(br, kk));
                acc1[nj] = __builtin_amdgcn_mfma_f32_16x16x32_bf16(aP[t], bfr, acc1[nj], 0, 0, 0);
            }
        }
        __syncthreads();   // Bh reads done
        WRT();             // write next stage (fus0 on last iter)
        __syncthreads();   // Bh ready
    }
    // GEMM1 epilogue: relu + cast -> bufI (swizzled [64][128])
    #pragma unroll
    for (int nj = 0; nj < 8; ++nj) {
        int col = nj * 16 + fr;
        float bv = enc_b[col];
        #pragma unroll
        for (int r = 0; r < 4; ++r) {
            int row = wv * 16 + fg * 4 + r;
            float val = fmaxf(acc1[nj][r] + bv, 0.f);
            bufI[row * 128 + SW(row, col)] = (short)f2bf(val);
        }
    }
    __syncthreads();   // bufI ready

    // af fragment loads (registers)
    bf16x8 af[4];
    {
        int ar = wv * 16 + fr;
        #pragma unroll
        for (int t = 0; t < 4; ++t)
            af[t] = *reinterpret_cast<const bf16x8*>(bufI + ar * 128 + SW(ar, fg * 8 + t * 32));
    }

    // ---------- GEMM2: xfus = bufI @ fus^T + fus_b, 2 half-phases (Bh holds fus0) ----------
    f32x4 acc2[8];
    #pragma unroll
    for (int j = 0; j < 8; ++j) acc2[j] = (f32x4){0.f, 0.f, 0.f, 0.f};

    // h = 0
    LDT(fus_img + 64 * 128);   // prefetch fus half 1
    #pragma unroll
    for (int t = 0; t < 4; ++t) {
        int k = t * 32 + fg * 8;
        #pragma unroll
        for (int nj = 0; nj < 4; ++nj) {
            int br = nj * 16 + fr;
            bf16x8 bfr = *reinterpret_cast<const bf16x8*>(Bh + br * 128 + SW(br, k));
            acc2[nj] = __builtin_amdgcn_mfma_f32_16x16x32_bf16(af[t], bfr, acc2[nj], 0, 0, 0);
        }
    }
    __syncthreads();
    WRT();
    __syncthreads();
    // h = 1
    LDT(c1_img);               // prefetch c1 chunk0 half0
    #pragma unroll
    for (int t = 0; t < 4; ++t) {
        int k = t * 32 + fg * 8;
        #pragma unroll
        for (int nj = 0; nj < 4; ++nj) {
            int br = nj * 16 + fr;
            bf16x8 bfr = *reinterpret_cast<const bf16x8*>(Bh + br * 128 + SW(br, k));
            acc2[4 + nj] = __builtin_amdgcn_mfma_f32_16x16x32_bf16(af[t], bfr, acc2[4 + nj], 0, 0, 0);
        }
    }
    __syncthreads();   // Bh reads done
    WRT();             // Bh <- c1[0] half0
    // GEMM2 epilogue -> bufI (af in regs; bufI reads long done)
    #pragma unroll
    for (int h = 0; h < 2; ++h)
        #pragma unroll
        for (int nj = 0; nj < 4; ++nj) {
            int col = h * 64 + nj * 16 + fr;
            float bv = fus_b[col];
            #pragma unroll
            for (int r = 0; r < 4; ++r) {
                int row = wv * 16 + fg * 4 + r;
                bufI[row * 128 + SW(row, col)] = (short)f2bf(acc2[h * 4 + nj][r] + bv);
            }
        }
    __syncthreads();   // Bh + bufI ready

    // af2 fragment loads
    bf16x8 af2[4];
    {
        int ar = wv * 16 + fr;
        #pragma unroll
        for (int t = 0; t < 4; ++t)
            af2[t] = *reinterpret_cast<const bf16x8*>(bufI + ar * 128 + SW(ar, fg * 8 + t * 32));
    }

    // ---------- GEMM3: qkvs = bufI @ c1^T + c1_b, 8 half-stages, bounce-store ----------
    f32x4 acc3[8];
    #pragma unroll
    for (int s = 0; s < 8; ++s) {
        int cc = s >> 1, h = s & 1;
        if (h == 0) {
            #pragma unroll
            for (int j = 0; j < 8; ++j) acc3[j] = (f32x4){0.f, 0.f, 0.f, 0.f};
        }
        if (s < 7) LDT(c1_img + (s + 1) * 8192);   // prefetch next half-stage
        #pragma unroll
        for (int t = 0; t < 4; ++t) {
            int k = t * 32 + fg * 8;
            #pragma unroll
            for (int nj = 0; nj < 4; ++nj) {
                int br = nj * 16 + fr;
                bf16x8 bfr = *reinterpret_cast<const bf16x8*>(Bh + br * 128 + SW(br, k));
                acc3[h * 4 + nj] = __builtin_amdgcn_mfma_f32_16x16x32_bf16(af2[t], bfr, acc3[h * 4 + nj], 0, 0, 0);
            }
        }
        if (h == 0) {
            __syncthreads();   // Bh reads done
            WRT();
            __syncthreads();   // Bh ready
        } else {
            __syncthreads();   // Bh reads + prior bounce-store LDS reads done
            if (s < 7) WRT();  // Bh <- next chunk half0
            // bounce: acc3 -> bufI linear (+bias)
            #pragma unroll
            for (int hh = 0; hh < 2; ++hh)
                #pragma unroll
                for (int nj = 0; nj < 4; ++nj) {
                    int col = hh * 64 + nj * 16 + fr;
                    float bv = c1_b[cc * 128 + col];
                    #pragma unroll
                    for (int r = 0; r < 4; ++r) {
                        int row = wv * 16 + fg * 4 + r;
                        bufI[row * 128 + col] = (short)f2bf(acc3[hh * 4 + nj][r] + bv);
                    }
                }
            __syncthreads();   // bufI + Bh ready
            // coalesced 16B/lane store of chunk cc
            #pragma unroll
            for (int i = 0; i < 4; ++i) {
                int p = tid + i * 256;
                int row = p >> 4;
                int c8 = (p & 15) * 8;
                int gr = bm + row;
                if (gr < M)
                    *reinterpret_cast<bf16x8*>(qkvs1 + (size_t)gr * 512 + cc * 128 + c8) =
                        *reinterpret_cast<const bf16x8*>(bufI + row * 128 + c8);
            }
        }
    }
    #undef LDT
    #undef WRT
}

// ---------------- LDS MFMA GEMM (conv2), swizzled, bounce-store epilogue ----------------
#define BM 128

template<int BNT>
__global__ __launch_bounds__(256) void gemm_mfma(
    const unsigned short* __restrict__ A, int lda, int M, int K,
    const unsigned short* __restrict__ Wt,
    const float* __restrict__ bias,
    unsigned short* __restrict__ C, int ldc)
{
    __shared__ __align__(16) short As[BM * 64];
    __shared__ __align__(16) short Bs[BNT * 64];
    const int tid = threadIdx.x;
    const int bm = blockIdx.x * BM;
    const int bn = blockIdx.y * BNT;
    const int tr = tid >> 4;
    const int tc = (tid & 15) * 4;
    const int l  = tid & 63;
    const int wv = tid >> 6;
    const int fr = l & 15;
    const int fg = l >> 4;

    f32x4 acc[2][BNT / 16];
    #pragma unroll
    for (int i = 0; i < 2; ++i)
        #pragma unroll
        for (int j = 0; j < BNT / 16; ++j) acc[i][j] = (f32x4){0.f, 0.f, 0.f, 0.f};

    for (int k0 = 0; k0 < K; k0 += 64) {
        #pragma unroll
        for (int p = 0; p < 8; ++p) {
            int row = p * 16 + tr;
            int grow = bm + row;
            int k = k0 + tc;
            bf16x4 s4 = (bf16x4){0, 0, 0, 0};
            if (grow < M) s4 = *reinterpret_cast<const bf16x4*>(A + (size_t)grow * lda + k);
            *reinterpret_cast<bf16x4*>(As + row * 64 + SW(row, tc)) = s4;
        }
        #pragma unroll
        for (int p = 0; p < BNT / 16; ++p) {
            int n = p * 16 + tr;
            *reinterpret_cast<bf16x4*>(Bs + n * 64 + SW(n, tc)) =
                *reinterpret_cast<const bf16x4*>(Wt + (size_t)(bn + n) * K + k0 + tc);
        }
        __syncthreads();
        #pragma unroll
        for (int ks = 0; ks < 2; ++ks) {
            int kk = ks * 32 + fg * 8;
            int ar0 = wv * 32 + fr, ar1 = wv * 32 + 16 + fr;
            bf16x8 a0 = *reinterpret_cast<const bf16x8*>(As + ar0 * 64 + SW(ar0, kk));
            bf16x8 a1 = *reinterpret_cast<const bf16x8*>(As + ar1 * 64 + SW(ar1, kk));
            #pragma unroll
            for (int nj = 0; nj < BNT / 16; ++nj) {
                int br = nj * 16 + fr;
                bf16x8 b = *reinterpret_cast<const bf16x8*>(Bs + br * 64 + SW(br, kk));
                acc[0][nj] = __builtin_amdgcn_mfma_f32_16x16x32_bf16(a0, b, acc[0][nj], 0, 0, 0);
                acc[1][nj] = __builtin_amdgcn_mfma_f32_16x16x32_bf16(a1, b, acc[1][nj], 0, 0, 0);
            }
        }
        __syncthreads();
    }
    #pragma unroll
    for (int mi = 0; mi < 2; ++mi) {
        #pragma unroll
        for (int nj = 0; nj < BNT / 16; ++nj) {
            int col = nj * 16 + fr;
            float bv = bias[bn + col];
            #pragma unroll
            for (int r = 0; r < 4; ++r) {
                int lr = wv * 16 + fg * 4 + r;
                As[lr * BNT + col] = (short)f2bf(acc[mi][nj][r] + bv);
            }
        }
        __syncthreads();
        #pragma unroll
        for (int i = 0; i < 4; ++i) {
            int p = tid + i * 256;
            int lr = p >> 4;
            int c8 = (p & 15) * 8;
            int grow = bm + (lr >> 4) * 32 + mi * 16 + (lr & 15);
            if (grow < M)
                *reinterpret_cast<bf16x8*>(C + (size_t)grow * ldc + bn + c8) =
                    *reinterpret_cast<const bf16x8*>(As + lr * BNT + c8);
        }
        __syncthreads();
    }
}

// ---------------- attention, heads=2; prefetch depth 2 ----------------
__global__ __launch_bounds__(256) void attn_h2(
    const unsigned short* __restrict__ qkvs,
    const int* __restrict__ rowptr, const int* __restrict__ esrc,
    unsigned short* __restrict__ outp, int N)
{
    int wid = (blockIdx.x * blockDim.x + threadIdx.x) >> 6;
    int l = threadIdx.x & 63;
    if (wid >= N) return;
    const int sl = l & 15;
    const int g  = l >> 4;
    const unsigned short* bi = qkvs + (size_t)wid * 512;
    float q[8];
    {
        bf16x8 qv = *reinterpret_cast<const bf16x8*>(bi + 8 * sl);
        #pragma unroll
        for (int i = 0; i < 8; ++i) q[i] = bf2f((unsigned short)qv[i]) * L2E8;
    }
    float s = 0.f;
    float acc[8] = {0.f, 0.f, 0.f, 0.f, 0.f, 0.f, 0.f, 0.f};
    const int beg = rowptr[wid], end = rowptr[wid + 1];
    const int iters = (end - beg + 3) >> 2;
    int e = beg + g;
    bool va0 = e < end;
    int j0 = va0 ? esrc[e] : wid;
    const unsigned short* pp0 = qkvs + (size_t)j0 * 512 + 8 * sl;
    bf16x8 ka = *reinterpret_cast<const bf16x8*>(pp0 + 128);
    bf16x8 vva = *reinterpret_cast<const bf16x8*>(pp0 + 256);
    bool va1 = (e + 4) < end;
    int j1 = va1 ? esrc[e + 4] : wid;
    const unsigned short* pp1 = qkvs + (size_t)j1 * 512 + 8 * sl;
    bf16x8 kb = *reinterpret_cast<const bf16x8*>(pp1 + 128);
    bf16x8 vvb = *reinterpret_cast<const bf16x8*>(pp1 + 256);
    for (int it = 0; it < iters; ++it) {
        bf16x8 kc = ka, vc = vva;
        bool vd = va0;
        ka = kb; vva = vvb; va0 = va1;
        va1 = (e + 8) < end;
        int j2 = va1 ? esrc[e + 8] : wid;
        const unsigned short* p2 = qkvs + (size_t)j2 * 512 + 8 * sl;
        kb = *reinterpret_cast<const bf16x8*>(p2 + 128);
        vvb = *reinterpret_cast<const bf16x8*>(p2 + 256);
        e += 4;
        float p = 0.f;
        #pragma unroll
        for (int i = 0; i < 8; ++i) p += q[i] * bf2f((unsigned short)kc[i]);
        p += __shfl_xor(p, 1, 64);
        p += __shfl_xor(p, 2, 64);
        p += __shfl_xor(p, 4, 64);
        float w = vd ? __builtin_amdgcn_exp2f(p) : 0.f;
        s += w;
        #pragma unroll
        for (int i = 0; i < 8; ++i) acc[i] += w * bf2f((unsigned short)vc[i]);
    }
    #pragma unroll
    for (int mask = 16; mask <= 32; mask <<= 1) {
        s += __shfl_xor(s, mask, 64);
        #pragma unroll
        for (int i = 0; i < 8; ++i) acc[i] += __shfl_xor(acc[i], mask, 64);
    }
    if (g == 0) {
        float inv = 1.f / (s + 1e-16f);
        bf16x8 sv = *reinterpret_cast<const bf16x8*>(bi + 384 + 8 * sl);
        bf16x8 o;
        #pragma unroll
        for (int i = 0; i < 8; ++i) {
            float r = fmaxf(acc[i] * inv + bf2f((unsigned short)sv[i]), 0.f);
            o[i] = (short)f2bf(r);
        }
        *reinterpret_cast<bf16x8*>(outp + (size_t)wid * 128 + 8 * sl) = o;
    }
}

// ---------------- attention, heads=1; prefetch depth 2 ----------------
__global__ __launch_bounds__(256) void attn_h1(
    const unsigned short* __restrict__ qkvs,
    const int* __restrict__ rowptr, const int* __restrict__ esrc,
    float* __restrict__ outp, int N)
{
    int wid = (blockIdx.x * blockDim.x + threadIdx.x) >> 6;
    int l = threadIdx.x & 63;
    if (wid >= N) return;
    const int sl = l & 7;
    const int g  = l >> 3;
    const unsigned short* bi = qkvs + (size_t)wid * 256;
    float q[8];
    {
        bf16x8 qv = *reinterpret_cast<const bf16x8*>(bi + 8 * sl);
        #pragma unroll
        for (int i = 0; i < 8; ++i) q[i] = bf2f((unsigned short)qv[i]) * L2E8;
    }
    float s = 0.f;
    float acc[8] = {0.f, 0.f, 0.f, 0.f, 0.f, 0.f, 0.f, 0.f};
    const int beg = rowptr[wid], end = rowptr[wid + 1];
    const int iters = (end - beg + 7) >> 3;
    int e = beg + g;
    bool va0 = e < end;
    int j0 = va0 ? esrc[e] : wid;
    const unsigned short* pp0 = qkvs + (size_t)j0 * 256 + 8 * sl;
    bf16x8 ka = *reinterpret_cast<const bf16x8*>(pp0 + 64);
    bf16x8 vva = *reinterpret_cast<const bf16x8*>(pp0 + 128);
    bool va1 = (e + 8) < end;
    int j1 = va1 ? esrc[e + 8] : wid;
    const unsigned short* pp1 = qkvs + (size_t)j1 * 256 + 8 * sl;
    bf16x8 kb = *reinterpret_cast<const bf16x8*>(pp1 + 64);
    bf16x8 vvb = *reinterpret_cast<const bf16x8*>(pp1 + 128);
    for (int it = 0; it < iters; ++it) {
        bf16x8 kc = ka, vc = vva;
        bool vd = va0;
        ka = kb; vva = vvb; va0 = va1;
        va1 = (e + 16) < end;
        int j2 = va1 ? esrc[e + 16] : wid;
        const unsigned short* p2 = qkvs + (size_t)j2 * 256 + 8 * sl;
        kb = *reinterpret_cast<const bf16x8*>(p2 + 64);
        vvb = *reinterpret_cast<const bf16x8*>(p2 + 128);
        e += 8;
        float p = 0.f;
        #pragma unroll
        for (int i = 0; i < 8; ++i) p += q[i] * bf2f((unsigned short)kc[i]);
        p += __shfl_xor(p, 1, 64);
        p += __shfl_xor(p, 2, 64);
        p += __shfl_xor(p, 4, 64);
        float w = vd ? __builtin_amdgcn_exp2f(p) : 0.f;
        s += w;
        #pragma unroll
        for (int i = 0; i < 8; ++i) acc[i] += w * bf2f((unsigned short)vc[i]);
    }
    #pragma unroll
    for (int mask = 8; mask <= 32; mask <<= 1) {
        s += __shfl_xor(s, mask, 64);
        #pragma unroll
        for (int i = 0; i < 8; ++i) acc[i] += __shfl_xor(acc[i], mask, 64);
    }
    if (g == 0) {
        float inv = 1.f / (s + 1e-16f);
        float r[8];
        #pragma unroll
        for (int i = 0; i < 8; ++i)
            r[i] = acc[i] * inv + bf2f(bi[192 + 8 * sl + i]);
        float* op = outp + (size_t)wid * 64 + 8 * sl;
        *reinterpret_cast<float4*>(op)     = make_float4(r[0], r[1], r[2], r[3]);
        *reinterpret_cast<float4*>(op + 4) = make_float4(r[4], r[5], r[6], r[7]);
    }
}

// ---------------- fused global mean pool + head MLP ----------------
__device__ __forceinline__ int lbound(const int* __restrict__ a, int n, int key) {
    int lo = 0, hi = n;
    while (lo < hi) {
        int mid = (lo + hi) >> 1;
        if (a[mid] < key) lo = mid + 1; else hi = mid;
    }
    return lo;
}

__global__ void pool_head(const float* __restrict__ h, const int* __restrict__ batch,
                          const float* __restrict__ l1W, const float* __restrict__ l1b,
                          const float* __restrict__ l2W, const float* __restrict__ l2b,
                          float* __restrict__ out) {
    __shared__ float red[4][64];
    int g = blockIdx.x;
    int l = threadIdx.x & 63;
    int w = threadIdx.x >> 6;
    int lo = lbound(batch, NNODES, g);
    int hi = lbound(batch, NNODES, g + 1);
    float s = 0.f;
    for (int i = lo + w; i < hi; i += 4) s += h[(size_t)i * 64 + l];
    red[w][l] = s;
    __syncthreads();
    if (w == 0) {
        float t = red[0][l] + red[1][l] + red[2][l] + red[3][l];
        float cnt = (float)((hi - lo) > 1 ? (hi - lo) : 1);
        float p = t / cnt;
        float hsum = l1b[l];
        #pragma unroll
        for (int kk = 0; kk < 64; ++kk) {
            float pk = __shfl(p, kk, 64);
            hsum += pk * l1W[kk * 64 + l];
        }
        float hr = fmaxf(hsum, 0.f);
        float o0 = hr * l2W[l * 2 + 0];
        float o1 = hr * l2W[l * 2 + 1];
        #pragma unroll
        for (int off = 32; off > 0; off >>= 1) {
            o0 += __shfl_xor(o0, off, 64);
            o1 += __shfl_xor(o1, off, 64);
        }
        if (l == 0) {
            out[g * 2 + 0] = o0 + l2b[0];
            out[g * 2 + 1] = o1 + l2b[1];
        }
    }
}

// ---------------- host launch ----------------
extern "C" void kernel_launch(void* const* d_in, const int* in_sizes, int n_in,
                              void* d_out, int out_size, void* d_ws, size_t ws_size,
                              hipStream_t stream) {
    const float* x      = (const float*)d_in[0];
    const int*   ei     = (const int*)d_in[1];
    const int*   batch  = (const int*)d_in[2];
    const float* syn_W  = (const float*)d_in[3];  const float* syn_b = (const float*)d_in[4];
    const float* ant_W  = (const float*)d_in[5];  const float* ant_b = (const float*)d_in[6];
    const float* fus_W  = (const float*)d_in[7];  const float* fus_b = (const float*)d_in[8];
    const float* c1_Wq  = (const float*)d_in[9];  const float* c1_bq = (const float*)d_in[10];
    const float* c1_Wk  = (const float*)d_in[11]; const float* c1_bk = (const float*)d_in[12];
    const float* c1_Wv  = (const float*)d_in[13]; const float* c1_bv = (const float*)d_in[14];
    const float* c1_Ws  = (const float*)d_in[15]; const float* c1_bs = (const float*)d_in[16];
    const float* c2_Wq  = (const float*)d_in[17]; const float* c2_bq = (const float*)d_in[18];
    const float* c2_Wk  = (const float*)d_in[19]; const float* c2_bk = (const float*)d_in[20];
    const float* c2_Wv  = (const float*)d_in[21]; const float* c2_bv = (const float*)d_in[22];
    const float* c2_Ws  = (const float*)d_in[23]; const float* c2_bs = (const float*)d_in[24];
    const float* l1_W   = (const float*)d_in[25]; const float* l1_b  = (const float*)d_in[26];
    const float* l2_W   = (const float*)d_in[27]; const float* l2_b  = (const float*)d_in[28];
    const int* src = ei;
    const int* dst = ei + NEDGES;
    float* out = (float*)d_out;

    char* ws = (char*)d_ws;
    size_t off = 0;
    auto alloc = [&](size_t bytes) -> char* {
        char* p = ws + off;
        off += (bytes + 255) & ~((size_t)255);
        return p;
    };

    unsigned short* H     = (unsigned short*)alloc((size_t)NNODES * 128 * 2);
    unsigned short* H2b   = (unsigned short*)alloc((size_t)NNODES * 128 * 2);
    unsigned short* qkvs1 = (unsigned short*)alloc((size_t)NNODES * 512 * 2);
    unsigned short* qkvs2 = (unsigned short*)alloc((size_t)NNODES * 256 * 2);
    unsigned short* fus_img = (unsigned short*)alloc((size_t)16384 * 2);
    unsigned short* c1_img  = (unsigned short*)alloc((size_t)4 * 16384 * 2);
    unsigned short* c2w_t   = (unsigned short*)alloc((size_t)256 * 128 * 2);
    float* enc_b = (float*)alloc(128 * 4);
    float* c1_b  = (float*)alloc(512 * 4);
    float* c2_b  = (float*)alloc(256 * 4);
    int*   cursor = (int*)alloc((NNODES + 1) * 4);
    int*   rowptr = (int*)alloc((NNODES + 1) * 4);
    int*   bsum   = (int*)alloc(256 * 4);
    int*   esrc   = (int*)alloc((size_t)NEDGES * 4);
    // ---- contiguous zero region: deg | enc_img ----
    char* zbase = ws + off;
    int*   deg     = (int*)alloc((NNODES + 1) * 4);
    unsigned short* enc_img = (unsigned short*)alloc((size_t)5 * 8192 * 2);
    size_t zspan = (size_t)((ws + off) - zbase);

    const int NB = (NNODES + 255) / 256;
    dim3 t256(256);

    WTArgs wa;
    wa.w[0] = syn_W;  wa.o[0] = enc_img;  wa.K[0] = 300; wa.N[0] = 64;  wa.mode[0] = 1; wa.roff[0] = 0;
    wa.w[1] = ant_W;  wa.o[1] = enc_img;  wa.K[1] = 300; wa.N[1] = 64;  wa.mode[1] = 1; wa.roff[1] = 64;
    wa.w[2] = fus_W;  wa.o[2] = fus_img;  wa.K[2] = 128; wa.N[2] = 128; wa.mode[2] = 2; wa.roff[2] = 0;
    wa.w[3] = c1_Wq;  wa.o[3] = c1_img + 0 * 16384; wa.K[3] = 128; wa.N[3] = 128; wa.mode[3] = 2; wa.roff[3] = 0;
    wa.w[4] = c1_Wk;  wa.o[4] = c1_img + 1 * 16384; wa.K[4] = 128; wa.N[4] = 128; wa.mode[4] = 2; wa.roff[4] = 0;
    wa.w[5] = c1_Wv;  wa.o[5] = c1_img + 2 * 16384; wa.K[5] = 128; wa.N[5] = 128; wa.mode[5] = 2; wa.roff[5] = 0;
    wa.w[6] = c1_Ws;  wa.o[6] = c1_img + 3 * 16384; wa.K[6] = 128; wa.N[6] = 128; wa.mode[6] = 2; wa.roff[6] = 0;
    wa.w[7] = c2_Wq;  wa.o[7] = c2w_t + 0 * 64 * 128;  wa.K[7] = 128; wa.N[7] = 64; wa.mode[7] = 0; wa.roff[7] = 0;
    wa.w[8] = c2_Wk;  wa.o[8] = c2w_t + 1 * 64 * 128;  wa.K[8] = 128; wa.N[8] = 64; wa.mode[8] = 0; wa.roff[8] = 0;
    wa.w[9] = c2_Wv;  wa.o[9] = c2w_t + 2 * 64 * 128;  wa.K[9] = 128; wa.N[9] = 64; wa.mode[9] = 0; wa.roff[9] = 0;
    wa.w[10] = c2_Ws; wa.o[10] = c2w_t + 3 * 64 * 128; wa.K[10] = 128; wa.N[10] = 64; wa.mode[10] = 0; wa.roff[10] = 0;
    wa.syn_b = syn_b; wa.ant_b = ant_b;
    wa.c1q = c1_bq; wa.c1k = c1_bk; wa.c1v = c1_bv; wa.c1s = c1_bs;
    wa.c2q = c2_bq; wa.c2k = c2_bk; wa.c2v = c2_bv; wa.c2s = c2_bs;
    wa.enc_b = enc_b; wa.c1_b = c1_b; wa.c2_b = c2_b;

    // --- single memset for deg + enc_img(K-pad) ---
    hipMemsetAsync(zbase, 0, zspan, stream);
    // --- setup: hist ∥ weight images (independent) ---
    k_setup<<<EB + 900, t256, 0, stream>>>(wa, dst, deg);

    // --- scans (scan2 folded into scan3) ---
    k_scan1<<<NB, t256, 0, stream>>>(deg, rowptr, bsum, NNODES);
    k_scan3<<<NB, t256, 0, stream>>>(rowptr, bsum, cursor, NNODES, NEDGES, NB);

    // --- front (enc->fus->conv1) interleaved with fill ---
    k_front_fill<<<FF_GRID, t256, 0, stream>>>(
        x, enc_img, enc_b, fus_img, fus_b, c1_img, c1_b, qkvs1, NNODES,
        src, dst, cursor, esrc);

    // --- conv1 attention + relu -> H ---
    attn_h2<<<(NNODES * 64 + 255) / 256, t256, 0, stream>>>(qkvs1, rowptr, esrc, H, NNODES);

    // --- conv2 q|k|v|s, N=256 (BN=128, y=2) ---
    gemm_mfma<128><<<dim3((NNODES + BM - 1) / BM, 2), t256, 0, stream>>>(
        H, 128, NNODES, 128, c2w_t, c2_b, qkvs2, 256);

    // --- conv2 attention -> H2 (f32) ---
    float* H2 = (float*)H2b;
    attn_h1<<<(NNODES * 64 + 255) / 256, t256, 0, stream>>>(qkvs2, rowptr, esrc, H2, NNODES);

    // --- pool + head ---
    pool_head<<<NGRAPH, t256, 0, stream>>>(H2, batch, l1_W, l1_b, l2_W, l2_b, out);
}